// Round 14
// baseline (637.700 us; speedup 1.0000x reference)
//
#include <hip/hip_runtime.h>

typedef __attribute__((ext_vector_type(8))) short bf16x8;
typedef __attribute__((ext_vector_type(4))) float f32x4;

#define DEV __device__ __forceinline__

static constexpr int Bb = 4, Sq = 1024, Dd = 1024, Hh = 16, HDd = 64, Ff = 4096, Ee = 8;
static constexpr int Nn = Bb * Sq;   // 4096 tokens
static constexpr int TD = 3 * Dd;    // 3072
static constexpr int PMAX = 2 * Nn + Ee * 256;  // 256-aligned packed rows cap = 10240

DEV unsigned short f2bf(float x) {
  union { float f; unsigned u; } c; c.f = x;
  unsigned r = c.u + 0x7FFFu + ((c.u >> 16) & 1u);
  return (unsigned short)(r >> 16);
}

typedef const __attribute__((address_space(1))) unsigned int* gas_t;
typedef __attribute__((address_space(3))) unsigned int* las_t;
DEV void gload16(const void* g, void* l) {
  __builtin_amdgcn_global_load_lds((gas_t)g, (las_t)l, 16, 0, 0);
}

// ---------------- f32 -> bf16 conversion (grid = count/2048) ----------------
__global__ __launch_bounds__(256) void cvt_kernel(const float* __restrict__ in,
                                                  unsigned short* __restrict__ out) {
  int i = blockIdx.x * 256 + threadIdx.x;
  const float4 a = *(const float4*)(in + (size_t)i * 8);
  const float4 b = *(const float4*)(in + (size_t)i * 8 + 4);
  union { uint4 u; unsigned short s[8]; } pk;
  pk.s[0] = f2bf(a.x); pk.s[1] = f2bf(a.y); pk.s[2] = f2bf(a.z); pk.s[3] = f2bf(a.w);
  pk.s[4] = f2bf(b.x); pk.s[5] = f2bf(b.y); pk.s[6] = f2bf(b.z); pk.s[7] = f2bf(b.w);
  *(uint4*)(out + (size_t)i * 8) = pk.u;
}

// XCD-bijective chunking, by-fast decode (r11-verified)
DEV void xcd_swz(int& bx, int& by, int gx, int gy) {
  const int nwg = gx * gy;
  int orig = by * gx + bx;
  int q = nwg >> 3, r = nwg & 7;
  int xcd = orig & 7, lin = orig >> 3;
  int wg = (xcd < r ? xcd * (q + 1) : r * (q + 1) + (xcd - r) * q) + lin;
  bx = wg / gy; by = wg % gy;
}

// ============ 8-phase 256x256 MoE-up GEMM: hbuf = relu(xg*w1^T + b1) ============
__global__ __launch_bounds__(512) void gemm8p_up(
    const unsigned short* __restrict__ A, const unsigned short* __restrict__ Bw,
    const float* __restrict__ bias, unsigned short* __restrict__ o0,
    const int* __restrict__ poff) {
  constexpr int K = Dd;            // 1024
  constexpr int NT = K / 64;       // 16
  int bx = blockIdx.x, by = blockIdx.y;
  xcd_swz(bx, by, gridDim.x, gridDim.y);
  const int m0 = bx * 256;
  if (m0 >= poff[Ee]) return;
  int e = 0;
#pragma unroll
  for (int k = 1; k < Ee; ++k) if (m0 >= poff[k]) e = k;
  const int n0 = by * 256;
  const unsigned short* Bptr = Bw + (size_t)e * Ff * K;
  const float* biasptr = bias + e * Ff;

  __shared__ __align__(128) unsigned short As[2 * 256 * 64];
  __shared__ __align__(128) unsigned short Bs[2 * 256 * 64];

  const int tid = threadIdx.x;
  const int lane = tid & 63, wid = tid >> 6;
  const int aw = wid & 1, bw = wid >> 1;
  const int lr = lane & 15, lk = lane >> 4;

  const char* aS[2][2]; const char* bS[2][2]; int dOf[2];
#pragma unroll
  for (int it = 0; it < 2; ++it) {
    int b = it * 8192 + tid * 16;
    int r = b >> 7;
    int colb = (b & 127) ^ ((r & 7) << 4);
#pragma unroll
    for (int h = 0; h < 2; ++h) {
      aS[h][it] = (const char*)(A + (size_t)(m0 + h * 128 + r) * K) + colb;
      bS[h][it] = (const char*)(Bptr + (size_t)(n0 + h * 128 + r) * K) + colb;
    }
    dOf[it] = it * 8192 + wid * 1024;
  }
  int aO[2][2][4], bO[2][2][2];
#pragma unroll
  for (int h = 0; h < 2; ++h)
#pragma unroll
    for (int ks = 0; ks < 2; ++ks) {
#pragma unroll
      for (int mi = 0; mi < 4; ++mi) {
        int ra = h * 128 + aw * 64 + mi * 16 + lr;
        aO[h][ks][mi] = ra * 64 + (((ks * 4 + lk) ^ (ra & 7)) << 3);
      }
#pragma unroll
      for (int ni = 0; ni < 2; ++ni) {
        int rb = h * 128 + bw * 32 + ni * 16 + lr;
        bO[h][ks][ni] = rb * 64 + (((ks * 4 + lk) ^ (rb & 7)) << 3);
      }
    }

  f32x4 acc[4][4][2] = {};

  auto ST_A = [&](int t, int h) {
    int buf = t & 1;
#pragma unroll
    for (int it = 0; it < 2; ++it)
      gload16(aS[h][it] + (size_t)t * 128, (char*)As + buf * 32768 + h * 16384 + dOf[it]);
  };
  auto ST_B = [&](int t, int h) {
    int buf = t & 1;
#pragma unroll
    for (int it = 0; it < 2; ++it)
      gload16(bS[h][it] + (size_t)t * 128, (char*)Bs + buf * 32768 + h * 16384 + dOf[it]);
  };

  ST_A(0, 0); ST_B(0, 0); ST_B(0, 1); ST_A(0, 1);

  for (int t = 0; t < NT; ++t) {
    const unsigned short* Ab = As + (t & 1) * 16384;
    const unsigned short* Bb = Bs + (t & 1) * 16384;
#pragma unroll
    for (int p = 0; p < 4; ++p) {
      const int ah = p >> 1, bh = p & 1;
      if (t + 1 < NT) {
        if (p == 0)      ST_A(t + 1, 0);
        else if (p == 1) ST_B(t + 1, 0);
        else if (p == 2) ST_B(t + 1, 1);
        else             ST_A(t + 1, 1);
        asm volatile("s_waitcnt vmcnt(6)" ::: "memory");
      } else {
        if (p == 0)      asm volatile("s_waitcnt vmcnt(4)" ::: "memory");
        else if (p == 1) asm volatile("s_waitcnt vmcnt(2)" ::: "memory");
        else             asm volatile("s_waitcnt vmcnt(0)" ::: "memory");
      }
      __builtin_amdgcn_sched_barrier(0);
      asm volatile("s_barrier" ::: "memory");
      __builtin_amdgcn_sched_barrier(0);
      bf16x8 af[2][4], bf[2][2];
#pragma unroll
      for (int ks = 0; ks < 2; ++ks) {
#pragma unroll
        for (int mi = 0; mi < 4; ++mi) af[ks][mi] = *(const bf16x8*)&Ab[aO[ah][ks][mi]];
#pragma unroll
        for (int ni = 0; ni < 2; ++ni) bf[ks][ni] = *(const bf16x8*)&Bb[bO[bh][ks][ni]];
      }
      __builtin_amdgcn_s_setprio(1);
#pragma unroll
      for (int ks = 0; ks < 2; ++ks)
#pragma unroll
        for (int mi = 0; mi < 4; ++mi)
#pragma unroll
          for (int ni = 0; ni < 2; ++ni)
            acc[p][mi][ni] = __builtin_amdgcn_mfma_f32_16x16x32_bf16(af[ks][mi], bf[ks][ni], acc[p][mi][ni], 0, 0, 0);
      __builtin_amdgcn_s_setprio(0);
    }
  }

#pragma unroll
  for (int p = 0; p < 4; ++p)
#pragma unroll
    for (int ni = 0; ni < 2; ++ni) {
      const int col = n0 + (p & 1) * 128 + bw * 32 + ni * 16 + lr;
      const float bv = biasptr[col];
#pragma unroll
      for (int mi = 0; mi < 4; ++mi)
#pragma unroll
        for (int i = 0; i < 4; ++i) {
          const int row = m0 + (p >> 1) * 128 + aw * 64 + mi * 16 + lk * 4 + i;
          float v = acc[p][mi][ni][i] + bv;
          o0[(size_t)row * Ff + col] = f2bf(fmaxf(v, 0.f));
        }
    }
}

// ---------------- 128x128 GEMM, 3-buffer counted pipeline (r7-verified) ----------------
// EPI 0 (KS): QKV -> f32 linear slices o0 + kh*Nn*TD (no bias; combine adds it)
// EPI 1 (KS): outproj -> f32 slices o0 + kh*Nn*Dd, bias at kh==0
// EPI 3: MoE down grouped via poff -> ffp f32 (direct store)
template <int EPI, int KS = 1>
__global__ __launch_bounds__(256) void gemm_bt(
    const unsigned short* __restrict__ A, const unsigned short* __restrict__ Bw,
    const float* __restrict__ bias, void* __restrict__ o0, void* __restrict__ o1,
    void* __restrict__ o2, int M, int Ncols, int K,
    const int* __restrict__ poff) {
  const int kh = (KS > 1) ? blockIdx.z : 0;
  int bx = blockIdx.x, by = blockIdx.y;
  xcd_swz(bx, by, gridDim.x, gridDim.y);
  const int m0 = bx * 128;
  int e = 0;
  if constexpr (EPI == 3) {
    if (m0 >= poff[Ee]) return;
#pragma unroll
    for (int k = 1; k < Ee; ++k) if (m0 >= poff[k]) e = k;
  } else {
    if (m0 >= M) return;
  }
  const int n0 = by * 128;
  const int Kloc = K / KS;
  const int k00 = kh * Kloc;
  const unsigned short* Bptr = Bw + (size_t)e * Ncols * K;
  const float* biasptr = bias + e * Ncols;

  __shared__ __align__(128) unsigned short As[3 * 128 * 32];
  __shared__ __align__(128) unsigned short Bs[3 * 128 * 32];

  const int tid = threadIdx.x;
  const int lane = tid & 63, wid = tid >> 6;
  const int wm = wid >> 1, wn = wid & 1;
  const int lr = lane & 15, lk = lane >> 4;

  const char* aSrc[2]; const char* bSrc[2];
  int dOff[2];
#pragma unroll
  for (int it = 0; it < 2; ++it) {
    int b = it * 4096 + tid * 16;
    int r = b >> 6;
    int colb = (b & 63) ^ (((r >> 1) & 3) << 4);
    aSrc[it] = (const char*)(A + (size_t)(m0 + r) * K + k00) + colb;
    bSrc[it] = (const char*)(Bptr + (size_t)(n0 + r) * K + k00) + colb;
    dOff[it] = it * 4096 + wid * 1024;
  }
  int aOff[4], bOff[4];
#pragma unroll
  for (int i = 0; i < 4; ++i) {
    int ra = wm * 64 + i * 16 + lr;
    aOff[i] = ra * 32 + ((lk ^ ((ra >> 1) & 3)) << 3);
    int rb = wn * 64 + i * 16 + lr;
    bOff[i] = rb * 32 + ((lk ^ ((rb >> 1) & 3)) << 3);
  }

  auto STAGE = [&](int t, int buf) {
#pragma unroll
    for (int it = 0; it < 2; ++it) {
      gload16(aSrc[it] + (size_t)t * 64, (char*)As + buf * 8192 + dOff[it]);
      gload16(bSrc[it] + (size_t)t * 64, (char*)Bs + buf * 8192 + dOff[it]);
    }
  };

  f32x4 acc[4][4] = {};
  const int NT = Kloc >> 5;

  STAGE(0, 0);
  STAGE(1, 1);
  int cb = 0, sb = 2;
  for (int t = 0; t < NT; ++t) {
    if (t + 1 < NT) asm volatile("s_waitcnt vmcnt(4)" ::: "memory");
    else            asm volatile("s_waitcnt vmcnt(0)" ::: "memory");
    __builtin_amdgcn_sched_barrier(0);
    __builtin_amdgcn_s_barrier();
    __builtin_amdgcn_sched_barrier(0);
    if (t + 2 < NT) STAGE(t + 2, sb);
    const unsigned short* Ab = As + cb * 4096;
    const unsigned short* Bb2 = Bs + cb * 4096;
    bf16x8 af[4], bfv[4];
#pragma unroll
    for (int mi = 0; mi < 4; ++mi) af[mi] = *(const bf16x8*)&Ab[aOff[mi]];
#pragma unroll
    for (int ni = 0; ni < 4; ++ni) bfv[ni] = *(const bf16x8*)&Bb2[bOff[ni]];
#pragma unroll
    for (int mi = 0; mi < 4; ++mi)
#pragma unroll
      for (int ni = 0; ni < 4; ++ni)
        acc[mi][ni] = __builtin_amdgcn_mfma_f32_16x16x32_bf16(af[mi], bfv[ni], acc[mi][ni], 0, 0, 0);
    cb = (cb == 2) ? 0 : cb + 1;
    sb = (sb == 2) ? 0 : sb + 1;
  }

#pragma unroll
  for (int ni = 0; ni < 4; ++ni) {
    const int col = n0 + wn * 64 + ni * 16 + lr;
    const float bv = (EPI == 1 && kh == 0) ? biasptr[col] : (EPI == 3 ? biasptr[col] : 0.f);
#pragma unroll
    for (int mi = 0; mi < 4; ++mi) {
#pragma unroll
      for (int i = 0; i < 4; ++i) {
        const int mloc = wm * 64 + mi * 16 + lk * 4 + i;
        float v = acc[mi][ni][i] + bv;
        if constexpr (EPI == 0) {
          ((float*)o0)[((size_t)kh * Nn + m0 + mloc) * TD + col] = v;
        } else if constexpr (EPI == 1) {
          ((float*)o0)[((size_t)kh * Nn + m0 + mloc) * Dd + col] = v;
        } else {
          ((float*)o0)[(size_t)(m0 + mloc) * Dd + col] = v;
        }
      }
    }
  }
}

// ---- qkv combine: qkvtmp[0]+qkvtmp[1]+ipb -> bf16 head-layout scatter ----
__global__ __launch_bounds__(256) void qkv_combine_kernel(
    const float* __restrict__ tmp, const float* __restrict__ ipb,
    unsigned short* __restrict__ qb, unsigned short* __restrict__ kb,
    unsigned short* __restrict__ vb) {
  const size_t f = ((size_t)blockIdx.x * 256 + threadIdx.x) * 8;
  const float* t1 = tmp + (size_t)Nn * TD;
  float4 a0 = *(const float4*)(tmp + f);
  float4 a1 = *(const float4*)(tmp + f + 4);
  float4 b0 = *(const float4*)(t1 + f);
  float4 b1 = *(const float4*)(t1 + f + 4);
  const int t = (int)(f / TD), col = (int)(f % TD);
  float4 c0 = *(const float4*)(ipb + col);
  float4 c1 = *(const float4*)(ipb + col + 4);
  union { uint4 u; unsigned short s[8]; } pk;
  pk.s[0] = f2bf(a0.x + b0.x + c0.x); pk.s[1] = f2bf(a0.y + b0.y + c0.y);
  pk.s[2] = f2bf(a0.z + b0.z + c0.z); pk.s[3] = f2bf(a0.w + b0.w + c0.w);
  pk.s[4] = f2bf(a1.x + b1.x + c1.x); pk.s[5] = f2bf(a1.y + b1.y + c1.y);
  pk.s[6] = f2bf(a1.z + b1.z + c1.z); pk.s[7] = f2bf(a1.w + b1.w + c1.w);
  const int which = col >> 10, jj = col & 1023, hh = jj >> 6, hd = jj & 63;
  const int bb = t >> 10, s = t & 1023;
  unsigned short* dst = (which == 0) ? qb : (which == 1) ? kb : vb;
  *(uint4*)(dst + ((size_t)(bb * Hh + hh) * Sq + s) * HDd + hd) = pk.u;
}

// ---------------- flash attention, 64-row q tiles ----------------
__global__ __launch_bounds__(256) void attn_kernel(
    const unsigned short* __restrict__ qb, const unsigned short* __restrict__ kb,
    const unsigned short* __restrict__ vb, const int* __restrict__ mask,
    unsigned short* __restrict__ attnb) {
  const int qt = blockIdx.x, h = blockIdx.y, b = blockIdx.z;
  const unsigned short* Q = qb + (size_t)(b * Hh + h) * Sq * HDd;
  const unsigned short* Kg = kb + (size_t)(b * Hh + h) * Sq * HDd;
  const unsigned short* Vg = vb + (size_t)(b * Hh + h) * Sq * HDd;

  __shared__ unsigned short Qs[64 * 72], Ks[64 * 72], Vt[64 * 72], Ps[64 * 72];
  __shared__ float Ssm[64 * 65];
  __shared__ float mS[64], lS[64], aS[64];
  __shared__ int mk[64];

  const int tid = threadIdx.x, lane = tid & 63, wid = tid >> 6;
  const int lr = lane & 15, lk = lane >> 4;

#pragma unroll
  for (int it = 0; it < 2; ++it) {
    int c = tid + it * 256; int r = c >> 3, kc = (c & 7) * 8;
    *(uint4*)&Qs[r * 72 + kc] = *(const uint4*)(Q + (size_t)(qt * 64 + r) * 64 + kc);
  }
  if (tid < 64) { mS[tid] = -1e30f; lS[tid] = 0.f; }

  f32x4 oacc[4] = {};

  for (int kt = 0; kt < 16; ++kt) {
    __syncthreads();
#pragma unroll
    for (int it = 0; it < 2; ++it) {
      int c = tid + it * 256; int r = c >> 3, kc = (c & 7) * 8;
      *(uint4*)&Ks[r * 72 + kc] = *(const uint4*)(Kg + (size_t)(kt * 64 + r) * 64 + kc);
    }
    {
      int kk = tid >> 2, hg = (tid & 3) * 16;
      union { uint4 u[2]; unsigned short s[16]; } tv;
      tv.u[0] = *(const uint4*)(Vg + (size_t)(kt * 64 + kk) * 64 + hg);
      tv.u[1] = *(const uint4*)(Vg + (size_t)(kt * 64 + kk) * 64 + hg + 8);
#pragma unroll
      for (int j = 0; j < 16; ++j) Vt[(hg + j) * 72 + kk] = tv.s[j];
    }
    if (tid < 64) mk[tid] = mask[b * Sq + kt * 64 + tid];
    __syncthreads();

    f32x4 sacc[4] = {};
#pragma unroll
    for (int ks = 0; ks < 2; ++ks) {
      bf16x8 aq = *(const bf16x8*)&Qs[(wid * 16 + lr) * 72 + ks * 32 + lk * 8];
#pragma unroll
      for (int ni = 0; ni < 4; ++ni) {
        bf16x8 bk = *(const bf16x8*)&Ks[(ni * 16 + lr) * 72 + ks * 32 + lk * 8];
        sacc[ni] = __builtin_amdgcn_mfma_f32_16x16x32_bf16(aq, bk, sacc[ni], 0, 0, 0);
      }
    }
#pragma unroll
    for (int ni = 0; ni < 4; ++ni)
#pragma unroll
      for (int i = 0; i < 4; ++i) {
        int r = wid * 16 + lk * 4 + i, cc = ni * 16 + lr;
        float v = sacc[ni][i] * 0.125f;
        if (mk[cc] == 0) v = -1e30f;
        Ssm[r * 65 + cc] = v;
      }
    __syncthreads();
    {
      int r = tid >> 2, cg = (tid & 3) * 16;
      float xv[16];
#pragma unroll
      for (int j = 0; j < 16; ++j) xv[j] = Ssm[r * 65 + cg + j];
      float mx = xv[0];
#pragma unroll
      for (int j = 1; j < 16; ++j) mx = fmaxf(mx, xv[j]);
      mx = fmaxf(mx, __shfl_xor(mx, 1));
      mx = fmaxf(mx, __shfl_xor(mx, 2));
      float mprev = mS[r];
      float mnew = fmaxf(mprev, mx);
      float sum = 0.f;
      union { uint4 u[2]; unsigned short s[16]; } pb;
#pragma unroll
      for (int j = 0; j < 16; ++j) {
        float pv = expf(xv[j] - mnew);
        sum += pv; pb.s[j] = f2bf(pv);
      }
      sum += __shfl_xor(sum, 1);
      sum += __shfl_xor(sum, 2);
      *(uint4*)&Ps[r * 72 + cg] = pb.u[0];
      *(uint4*)&Ps[r * 72 + cg + 8] = pb.u[1];
      if ((tid & 3) == 0) {
        float alpha = expf(mprev - mnew);
        mS[r] = mnew; aS[r] = alpha; lS[r] = lS[r] * alpha + sum;
      }
    }
    __syncthreads();
#pragma unroll
    for (int ni = 0; ni < 4; ++ni)
#pragma unroll
      for (int i = 0; i < 4; ++i)
        oacc[ni][i] *= aS[wid * 16 + lk * 4 + i];
#pragma unroll
    for (int ks = 0; ks < 2; ++ks) {
      bf16x8 ap = *(const bf16x8*)&Ps[(wid * 16 + lr) * 72 + ks * 32 + lk * 8];
#pragma unroll
      for (int ni = 0; ni < 4; ++ni) {
        bf16x8 bv = *(const bf16x8*)&Vt[(ni * 16 + lr) * 72 + ks * 32 + lk * 8];
        oacc[ni] = __builtin_amdgcn_mfma_f32_16x16x32_bf16(ap, bv, oacc[ni], 0, 0, 0);
      }
    }
  }
  __syncthreads();
#pragma unroll
  for (int ni = 0; ni < 4; ++ni)
#pragma unroll
    for (int i = 0; i < 4; ++i) {
      int r = wid * 16 + lk * 4 + i;
      int q = qt * 64 + r;
      float v = oacc[ni][i] / lS[r];
      attnb[((size_t)(b * Sq + q)) * Dd + h * 64 + ni * 16 + lr] = f2bf(v);
    }
}

// ------- ln1 + gate routing fused: x1 = LN(x + sum_{j<4} proj[j]); route top-2 -------
__global__ __launch_bounds__(256) void ln1_route_kernel(
    const float* __restrict__ a, const float* __restrict__ proj4,
    const float* __restrict__ g, const float* __restrict__ beta,
    const float* __restrict__ gw, const float* __restrict__ gb,
    float* __restrict__ outf, unsigned short* __restrict__ outb,
    int* __restrict__ cnt, int* __restrict__ tokslot, float* __restrict__ wtok) {
  const int t = blockIdx.x, tid = threadIdx.x;
  float4 v = *(const float4*)(a + (size_t)t * Dd + tid * 4);
#pragma unroll
  for (int j = 0; j < 4; ++j) {
    float4 u = *(const float4*)(proj4 + ((size_t)j * Nn + t) * Dd + tid * 4);
    v.x += u.x; v.y += u.y; v.z += u.z; v.w += u.w;
  }
  const int lane = tid & 63, wid = tid >> 6;
  float s = v.x + v.y + v.z + v.w;
  for (int sh = 1; sh < 64; sh <<= 1) s += __shfl_xor(s, sh);
  __shared__ float red[4], red2[4];
  __shared__ float gred[4 * Ee];
  if (lane == 0) red[wid] = s;
  __syncthreads();
  float mean = (red[0] + red[1] + red[2] + red[3]) * (1.f / Dd);
  float dx = v.x - mean, dy = v.y - mean, dz = v.z - mean, dw = v.w - mean;
  float q = dx * dx + dy * dy + dz * dz + dw * dw;
  for (int sh = 1; sh < 64; sh <<= 1) q += __shfl_xor(q, sh);
  if (lane == 0) red2[wid] = q;
  __syncthreads();
  float var = (red2[0] + red2[1] + red2[2] + red2[3]) * (1.f / Dd);
  float rstd = rsqrtf(var + 1e-5f);
  float4 gg = *(const float4*)(g + tid * 4);
  float4 bbv = *(const float4*)(beta + tid * 4);
  float4 o;
  o.x = dx * rstd * gg.x + bbv.x;
  o.y = dy * rstd * gg.y + bbv.y;
  o.z = dz * rstd * gg.z + bbv.z;
  o.w = dw * rstd * gg.w + bbv.w;
  *(float4*)(outf + (size_t)t * Dd + tid * 4) = o;
  {
    ushort4 pk; pk.x = f2bf(o.x); pk.y = f2bf(o.y); pk.z = f2bf(o.z); pk.w = f2bf(o.w);
    *(ushort4*)(outb + (size_t)t * Dd + tid * 4) = pk;
  }
  float gacc[Ee];
#pragma unroll
  for (int e = 0; e < Ee; ++e) {
    float4 gv = *(const float4*)(gw + (size_t)e * Dd + tid * 4);
    gacc[e] = o.x * gv.x + o.y * gv.y + o.z * gv.z + o.w * gv.w;
  }
#pragma unroll
  for (int e = 0; e < Ee; ++e)
    for (int sh = 1; sh < 64; sh <<= 1) gacc[e] += __shfl_xor(gacc[e], sh);
  if (lane == 0) {
#pragma unroll
    for (int e = 0; e < Ee; ++e) gred[wid * Ee + e] = gacc[e];
  }
  __syncthreads();
  if (tid == 0) {
    float lg[Ee];
#pragma unroll
    for (int e = 0; e < Ee; ++e)
      lg[e] = gred[e] + gred[Ee + e] + gred[2 * Ee + e] + gred[3 * Ee + e] + gb[e];
    float m = lg[0];
#pragma unroll
    for (int e = 1; e < Ee; ++e) m = fmaxf(m, lg[e]);
    float p[Ee], ssum = 0.f;
#pragma unroll
    for (int e = 0; e < Ee; ++e) { p[e] = expf(lg[e] - m); ssum += p[e]; }
    int e0 = 0;
#pragma unroll
    for (int e = 1; e < Ee; ++e) if (p[e] > p[e0]) e0 = e;
    int e1 = -1;
#pragma unroll
    for (int e = 0; e < Ee; ++e) {
      if (e == e0) continue;
      if (e1 < 0 || p[e] > p[e1]) e1 = e;
    }
    float v0 = p[e0] / ssum, v1 = p[e1] / ssum;
    float wsum = v0 + v1 + 1e-9f;
    wtok[t * 2] = v0 / wsum; wtok[t * 2 + 1] = v1 / wsum;
    int p0 = atomicAdd(&cnt[e0], 1);
    tokslot[e0 * Nn + p0] = t * 2;
    int p1 = atomicAdd(&cnt[e1], 1);
    tokslot[e1 * Nn + p1] = t * 2 + 1;
  }
}

// ---- ln2: x1f + w0*ffp[i0] + w1*ffp[i1] -> LN -> out ----
__global__ __launch_bounds__(256) void ln2_kernel(
    const float* __restrict__ x1f, const float* __restrict__ ffp,
    const int* __restrict__ inv, const float* __restrict__ wtok,
    const float* __restrict__ g, const float* __restrict__ beta,
    float* __restrict__ out) {
  const int t = blockIdx.x, tid = threadIdx.x;
  const int i0 = inv[2 * t], i1 = inv[2 * t + 1];
  const float w0 = wtok[2 * t], w1 = wtok[2 * t + 1];
  float4 v = *(const float4*)(x1f + (size_t)t * Dd + tid * 4);
  float4 u0 = *(const float4*)(ffp + (size_t)i0 * Dd + tid * 4);
  float4 u1 = *(const float4*)(ffp + (size_t)i1 * Dd + tid * 4);
  v.x += w0 * u0.x + w1 * u1.x; v.y += w0 * u0.y + w1 * u1.y;
  v.z += w0 * u0.z + w1 * u1.z; v.w += w0 * u0.w + w1 * u1.w;
  const int lane = tid & 63, wid = tid >> 6;
  float s = v.x + v.y + v.z + v.w;
  for (int sh = 1; sh < 64; sh <<= 1) s += __shfl_xor(s, sh);
  __shared__ float red[4], red2[4];
  if (lane == 0) red[wid] = s;
  __syncthreads();
  float mean = (red[0] + red[1] + red[2] + red[3]) * (1.f / Dd);
  float dx = v.x - mean, dy = v.y - mean, dz = v.z - mean, dw = v.w - mean;
  float q = dx * dx + dy * dy + dz * dz + dw * dw;
  for (int sh = 1; sh < 64; sh <<= 1) q += __shfl_xor(q, sh);
  if (lane == 0) red2[wid] = q;
  __syncthreads();
  float var = (red2[0] + red2[1] + red2[2] + red2[3]) * (1.f / Dd);
  float rstd = rsqrtf(var + 1e-5f);
  float4 gg = *(const float4*)(g + tid * 4);
  float4 bb = *(const float4*)(beta + tid * 4);
  float4 o;
  o.x = dx * rstd * gg.x + bb.x;
  o.y = dy * rstd * gg.y + bb.y;
  o.z = dz * rstd * gg.z + bb.z;
  o.w = dw * rstd * gg.w + bb.w;
  *(float4*)(out + (size_t)t * Dd + tid * 4) = o;
}

// poff[e] = 256-aligned cumulative offsets; poff[Ee] = padded total
__global__ void offsets_kernel(const int* __restrict__ cnt, int* __restrict__ poff) {
  if (threadIdx.x == 0) {
    int s = 0;
    for (int e = 0; e < Ee; ++e) { poff[e] = s; s += (cnt[e] + 255) & ~255; }
    poff[Ee] = s;
  }
}

// ---------------- pack: gather x1b rows into padded xg, build inverse map ----------------
__global__ __launch_bounds__(256) void pack_kernel(
    const unsigned short* __restrict__ x1b, const int* __restrict__ tokslot,
    const int* __restrict__ cnt, const int* __restrict__ poff,
    unsigned short* __restrict__ xg, int* __restrict__ inv) {
  const int tid = threadIdx.x;
  const int g = blockIdx.x * 8 + (tid >> 5);
  const int l = tid & 31;
  if (g >= poff[Ee]) return;
  int e = 0;
#pragma unroll
  for (int k = 1; k < Ee; ++k) if (g >= poff[k]) e = k;
  const int pos = g - poff[e];
  uint4* dst = (uint4*)(xg + (size_t)g * Dd);
  if (pos < cnt[e]) {
    const int ent = tokslot[e * Nn + pos];
    if (l == 0) inv[ent] = g;
    const uint4* src = (const uint4*)(x1b + (size_t)(ent >> 1) * Dd);
#pragma unroll
    for (int j = 0; j < 4; ++j) dst[l + j * 32] = src[l + j * 32];
  } else {
    const uint4 z = make_uint4(0, 0, 0, 0);
#pragma unroll
    for (int j = 0; j < 4; ++j) dst[l + j * 32] = z;
  }
}

// ---------------- launch ----------------
extern "C" void kernel_launch(void* const* d_in, const int* in_sizes, int n_in,
                              void* d_out, int out_size, void* d_ws, size_t ws_size,
                              hipStream_t stream) {
  const float* x   = (const float*)d_in[0];
  const int*   msk = (const int*)d_in[1];
  const float* ipw = (const float*)d_in[2];
  const float* ipb = (const float*)d_in[3];
  const float* opw = (const float*)d_in[4];
  const float* opb = (const float*)d_in[5];
  const float* g1  = (const float*)d_in[6];
  const float* be1 = (const float*)d_in[7];
  const float* g2  = (const float*)d_in[8];
  const float* be2 = (const float*)d_in[9];
  const float* gw  = (const float*)d_in[10];
  const float* gb  = (const float*)d_in[11];
  const float* w1  = (const float*)d_in[12];
  const float* b1  = (const float*)d_in[13];
  const float* w2  = (const float*)d_in[14];
  const float* b2  = (const float*)d_in[15];
  float* out = (float*)d_out;

  char* p = (char*)d_ws;
  auto carve = [&](size_t bytes) { char* r = p; p += (bytes + 255) & ~(size_t)255; return r; };
  unsigned short* xb   = (unsigned short*)carve((size_t)Nn * Dd * 2);  // also attnb
  unsigned short* qb   = (unsigned short*)carve((size_t)Nn * Dd * 2);
  unsigned short* kb   = (unsigned short*)carve((size_t)Nn * Dd * 2);
  unsigned short* vb   = (unsigned short*)carve((size_t)Nn * Dd * 2);
  float* x1f           = (float*)carve((size_t)Nn * Dd * 4);
  unsigned short* x1b  = (unsigned short*)carve((size_t)Nn * Dd * 2);
  unsigned short* xg   = (unsigned short*)carve((size_t)PMAX * Dd * 2);
  float* ffp           = (float*)carve((size_t)PMAX * Dd * 4);          // 40MB
  unsigned short* hbuf = (unsigned short*)carve((size_t)PMAX * Ff * 2); // 80MB
  unsigned short* wbuf = (unsigned short*)carve((size_t)Ee * Ff * Dd * 2);
  int* cnt             = (int*)carve(64);
  int* poff            = (int*)carve(64);
  int* tokslot         = (int*)carve((size_t)Ee * Nn * 4);
  float* wtok          = (float*)carve((size_t)2 * Nn * 4);
  int* inv             = (int*)carve((size_t)2 * Nn * 4);
  unsigned short* attnb = xb;
  // time-shared aliases in the ffp+hbuf region (120MB contiguous):
  //   qkvtmp (2*Nn*TD*4 = 96MB): QKV f32 slices, dead after qkv_combine
  //   proj4  (4*Nn*Dd*4 = 64MB): outproj f32 slices, dead after ln1_route
  float* qkvtmp = ffp;
  float* proj4  = ffp;

  cvt_kernel<<<Nn * Dd / 2048, 256, 0, stream>>>(x, xb);
  cvt_kernel<<<TD * Dd / 2048, 256, 0, stream>>>(ipw, wbuf);
  gemm_bt<0, 2><<<dim3(Nn / 128, TD / 128, 2), 256, 0, stream>>>(
      xb, wbuf, ipb, qkvtmp, nullptr, nullptr, Nn, TD, Dd, nullptr);
  qkv_combine_kernel<<<Nn * TD / 2048, 256, 0, stream>>>(qkvtmp, ipb, qb, kb, vb);
  attn_kernel<<<dim3(Sq / 64, Hh, Bb), 256, 0, stream>>>(qb, kb, vb, msk, attnb);
  cvt_kernel<<<Dd * Dd / 2048, 256, 0, stream>>>(opw, wbuf);
  gemm_bt<1, 4><<<dim3(Nn / 128, Dd / 128, 4), 256, 0, stream>>>(
      attnb, wbuf, opb, proj4, nullptr, nullptr, Nn, Dd, Dd, nullptr);
  hipMemsetAsync(cnt, 0, 64, stream);
  ln1_route_kernel<<<Nn, 256, 0, stream>>>(x, proj4, g1, be1, gw, gb,
                                           x1f, x1b, cnt, tokslot, wtok);
  offsets_kernel<<<1, 64, 0, stream>>>(cnt, poff);
  pack_kernel<<<PMAX / 8, 256, 0, stream>>>(x1b, tokslot, cnt, poff, xg, inv);
  cvt_kernel<<<Ee * Ff * Dd / 2048, 256, 0, stream>>>(w1, wbuf);
  gemm8p_up<<<dim3(PMAX / 256, Ff / 256), 512, 0, stream>>>(xg, wbuf, b1, hbuf, poff);
  cvt_kernel<<<Ee * Dd * Ff / 2048, 256, 0, stream>>>(w2, wbuf);
  gemm_bt<3, 1><<<dim3(PMAX / 128, Dd / 128), 256, 0, stream>>>(
      hbuf, wbuf, b2, ffp, nullptr, nullptr, PMAX, Dd, Ff, poff);
  ln2_kernel<<<Nn, 256, 0, stream>>>(x1f, ffp, inv, wtok, g2, be2, out);
}

// Round 15
// 605.855 us; speedup vs baseline: 1.0526x; 1.0526x over previous
//
#include <hip/hip_runtime.h>

typedef __attribute__((ext_vector_type(8))) short bf16x8;
typedef __attribute__((ext_vector_type(4))) float f32x4;

#define DEV __device__ __forceinline__

static constexpr int Bb = 4, Sq = 1024, Dd = 1024, Hh = 16, HDd = 64, Ff = 4096, Ee = 8;
static constexpr int Nn = Bb * Sq;   // 4096 tokens
static constexpr int TD = 3 * Dd;    // 3072
static constexpr int PMAX = 2 * Nn + Ee * 256;  // 256-aligned packed rows cap = 10240

DEV unsigned short f2bf(float x) {
  union { float f; unsigned u; } c; c.f = x;
  unsigned r = c.u + 0x7FFFu + ((c.u >> 16) & 1u);
  return (unsigned short)(r >> 16);
}
DEV float bf2f(unsigned short u) {
  union { unsigned u; float f; } c; c.u = ((unsigned)u) << 16; return c.f;
}

typedef const __attribute__((address_space(1))) unsigned int* gas_t;
typedef __attribute__((address_space(3))) unsigned int* las_t;
DEV void gload16(const void* g, void* l) {
  __builtin_amdgcn_global_load_lds((gas_t)g, (las_t)l, 16, 0, 0);
}

// ---------------- f32 -> bf16 conversion (grid = count/2048) ----------------
__global__ __launch_bounds__(256) void cvt_kernel(const float* __restrict__ in,
                                                  unsigned short* __restrict__ out) {
  int i = blockIdx.x * 256 + threadIdx.x;
  const float4 a = *(const float4*)(in + (size_t)i * 8);
  const float4 b = *(const float4*)(in + (size_t)i * 8 + 4);
  union { uint4 u; unsigned short s[8]; } pk;
  pk.s[0] = f2bf(a.x); pk.s[1] = f2bf(a.y); pk.s[2] = f2bf(a.z); pk.s[3] = f2bf(a.w);
  pk.s[4] = f2bf(b.x); pk.s[5] = f2bf(b.y); pk.s[6] = f2bf(b.z); pk.s[7] = f2bf(b.w);
  *(uint4*)(out + (size_t)i * 8) = pk.u;
}

// XCD-bijective chunking, by-fast decode (r11-verified)
DEV void xcd_swz(int& bx, int& by, int gx, int gy) {
  const int nwg = gx * gy;
  int orig = by * gx + bx;
  int q = nwg >> 3, r = nwg & 7;
  int xcd = orig & 7, lin = orig >> 3;
  int wg = (xcd < r ? xcd * (q + 1) : r * (q + 1) + (xcd - r) * q) + lin;
  bx = wg / gy; by = wg % gy;
}

// ============ 8-phase 256x256 MoE-up GEMM: hbuf = relu(xg*w1^T + b1) ============
__global__ __launch_bounds__(512) void gemm8p_up(
    const unsigned short* __restrict__ A, const unsigned short* __restrict__ Bw,
    const float* __restrict__ bias, unsigned short* __restrict__ o0,
    const int* __restrict__ poff) {
  constexpr int K = Dd;            // 1024
  constexpr int NT = K / 64;       // 16
  int bx = blockIdx.x, by = blockIdx.y;
  xcd_swz(bx, by, gridDim.x, gridDim.y);
  const int m0 = bx * 256;
  if (m0 >= poff[Ee]) return;
  int e = 0;
#pragma unroll
  for (int k = 1; k < Ee; ++k) if (m0 >= poff[k]) e = k;
  const int n0 = by * 256;
  const unsigned short* Bptr = Bw + (size_t)e * Ff * K;
  const float* biasptr = bias + e * Ff;

  __shared__ __align__(128) unsigned short As[2 * 256 * 64];
  __shared__ __align__(128) unsigned short Bs[2 * 256 * 64];

  const int tid = threadIdx.x;
  const int lane = tid & 63, wid = tid >> 6;
  const int aw = wid & 1, bw = wid >> 1;
  const int lr = lane & 15, lk = lane >> 4;

  const char* aS[2][2]; const char* bS[2][2]; int dOf[2];
#pragma unroll
  for (int it = 0; it < 2; ++it) {
    int b = it * 8192 + tid * 16;
    int r = b >> 7;
    int colb = (b & 127) ^ ((r & 7) << 4);
#pragma unroll
    for (int h = 0; h < 2; ++h) {
      aS[h][it] = (const char*)(A + (size_t)(m0 + h * 128 + r) * K) + colb;
      bS[h][it] = (const char*)(Bptr + (size_t)(n0 + h * 128 + r) * K) + colb;
    }
    dOf[it] = it * 8192 + wid * 1024;
  }
  int aO[2][2][4], bO[2][2][2];
#pragma unroll
  for (int h = 0; h < 2; ++h)
#pragma unroll
    for (int ks = 0; ks < 2; ++ks) {
#pragma unroll
      for (int mi = 0; mi < 4; ++mi) {
        int ra = h * 128 + aw * 64 + mi * 16 + lr;
        aO[h][ks][mi] = ra * 64 + (((ks * 4 + lk) ^ (ra & 7)) << 3);
      }
#pragma unroll
      for (int ni = 0; ni < 2; ++ni) {
        int rb = h * 128 + bw * 32 + ni * 16 + lr;
        bO[h][ks][ni] = rb * 64 + (((ks * 4 + lk) ^ (rb & 7)) << 3);
      }
    }

  f32x4 acc[4][4][2] = {};

  auto ST_A = [&](int t, int h) {
    int buf = t & 1;
#pragma unroll
    for (int it = 0; it < 2; ++it)
      gload16(aS[h][it] + (size_t)t * 128, (char*)As + buf * 32768 + h * 16384 + dOf[it]);
  };
  auto ST_B = [&](int t, int h) {
    int buf = t & 1;
#pragma unroll
    for (int it = 0; it < 2; ++it)
      gload16(bS[h][it] + (size_t)t * 128, (char*)Bs + buf * 32768 + h * 16384 + dOf[it]);
  };

  ST_A(0, 0); ST_B(0, 0); ST_B(0, 1); ST_A(0, 1);

  for (int t = 0; t < NT; ++t) {
    const unsigned short* Ab = As + (t & 1) * 16384;
    const unsigned short* Bb = Bs + (t & 1) * 16384;
#pragma unroll
    for (int p = 0; p < 4; ++p) {
      const int ah = p >> 1, bh = p & 1;
      if (t + 1 < NT) {
        if (p == 0)      ST_A(t + 1, 0);
        else if (p == 1) ST_B(t + 1, 0);
        else if (p == 2) ST_B(t + 1, 1);
        else             ST_A(t + 1, 1);
        asm volatile("s_waitcnt vmcnt(6)" ::: "memory");
      } else {
        if (p == 0)      asm volatile("s_waitcnt vmcnt(4)" ::: "memory");
        else if (p == 1) asm volatile("s_waitcnt vmcnt(2)" ::: "memory");
        else             asm volatile("s_waitcnt vmcnt(0)" ::: "memory");
      }
      __builtin_amdgcn_sched_barrier(0);
      asm volatile("s_barrier" ::: "memory");
      __builtin_amdgcn_sched_barrier(0);
      bf16x8 af[2][4], bf[2][2];
#pragma unroll
      for (int ks = 0; ks < 2; ++ks) {
#pragma unroll
        for (int mi = 0; mi < 4; ++mi) af[ks][mi] = *(const bf16x8*)&Ab[aO[ah][ks][mi]];
#pragma unroll
        for (int ni = 0; ni < 2; ++ni) bf[ks][ni] = *(const bf16x8*)&Bb[bO[bh][ks][ni]];
      }
      __builtin_amdgcn_s_setprio(1);
#pragma unroll
      for (int ks = 0; ks < 2; ++ks)
#pragma unroll
        for (int mi = 0; mi < 4; ++mi)
#pragma unroll
          for (int ni = 0; ni < 2; ++ni)
            acc[p][mi][ni] = __builtin_amdgcn_mfma_f32_16x16x32_bf16(af[ks][mi], bf[ks][ni], acc[p][mi][ni], 0, 0, 0);
      __builtin_amdgcn_s_setprio(0);
    }
  }

#pragma unroll
  for (int p = 0; p < 4; ++p)
#pragma unroll
    for (int ni = 0; ni < 2; ++ni) {
      const int col = n0 + (p & 1) * 128 + bw * 32 + ni * 16 + lr;
      const float bv = biasptr[col];
#pragma unroll
      for (int mi = 0; mi < 4; ++mi)
#pragma unroll
        for (int i = 0; i < 4; ++i) {
          const int row = m0 + (p >> 1) * 128 + aw * 64 + mi * 16 + lk * 4 + i;
          float v = acc[p][mi][ni][i] + bv;
          o0[(size_t)row * Ff + col] = f2bf(fmaxf(v, 0.f));
        }
    }
}

// ---------------- 128x128 GEMM, 3-buffer counted pipeline (r7-verified) ----------------
// EPI 0: QKV -> qb/kb/vb head layout bf16; EPI 1: outproj -> proj f32;
// EPI 3: MoE down grouped via poff -> ffp bf16 (direct store)
template <int EPI>
__global__ __launch_bounds__(256) void gemm_bt(
    const unsigned short* __restrict__ A, const unsigned short* __restrict__ Bw,
    const float* __restrict__ bias, void* __restrict__ o0, void* __restrict__ o1,
    void* __restrict__ o2, int M, int Ncols, int K,
    const int* __restrict__ poff) {
  int bx = blockIdx.x, by = blockIdx.y;
  xcd_swz(bx, by, gridDim.x, gridDim.y);
  const int m0 = bx * 128;
  int e = 0;
  if constexpr (EPI == 3) {
    if (m0 >= poff[Ee]) return;
#pragma unroll
    for (int k = 1; k < Ee; ++k) if (m0 >= poff[k]) e = k;
  } else {
    if (m0 >= M) return;
  }
  const int n0 = by * 128;
  const unsigned short* Bptr = Bw + (size_t)e * Ncols * K;
  const float* biasptr = bias + e * Ncols;

  __shared__ __align__(128) unsigned short As[3 * 128 * 32];
  __shared__ __align__(128) unsigned short Bs[3 * 128 * 32];

  const int tid = threadIdx.x;
  const int lane = tid & 63, wid = tid >> 6;
  const int wm = wid >> 1, wn = wid & 1;
  const int lr = lane & 15, lk = lane >> 4;

  const char* aSrc[2]; const char* bSrc[2];
  int dOff[2];
#pragma unroll
  for (int it = 0; it < 2; ++it) {
    int b = it * 4096 + tid * 16;
    int r = b >> 6;
    int colb = (b & 63) ^ (((r >> 1) & 3) << 4);
    aSrc[it] = (const char*)(A + (size_t)(m0 + r) * K) + colb;
    bSrc[it] = (const char*)(Bptr + (size_t)(n0 + r) * K) + colb;
    dOff[it] = it * 4096 + wid * 1024;
  }
  int aOff[4], bOff[4];
#pragma unroll
  for (int i = 0; i < 4; ++i) {
    int ra = wm * 64 + i * 16 + lr;
    aOff[i] = ra * 32 + ((lk ^ ((ra >> 1) & 3)) << 3);
    int rb = wn * 64 + i * 16 + lr;
    bOff[i] = rb * 32 + ((lk ^ ((rb >> 1) & 3)) << 3);
  }

  auto STAGE = [&](int t, int buf) {
#pragma unroll
    for (int it = 0; it < 2; ++it) {
      gload16(aSrc[it] + (size_t)t * 64, (char*)As + buf * 8192 + dOff[it]);
      gload16(bSrc[it] + (size_t)t * 64, (char*)Bs + buf * 8192 + dOff[it]);
    }
  };

  f32x4 acc[4][4] = {};
  const int NT = K >> 5;

  STAGE(0, 0);
  STAGE(1, 1);
  int cb = 0, sb = 2;
  for (int t = 0; t < NT; ++t) {
    if (t + 1 < NT) asm volatile("s_waitcnt vmcnt(4)" ::: "memory");
    else            asm volatile("s_waitcnt vmcnt(0)" ::: "memory");
    __builtin_amdgcn_sched_barrier(0);
    __builtin_amdgcn_s_barrier();
    __builtin_amdgcn_sched_barrier(0);
    if (t + 2 < NT) STAGE(t + 2, sb);
    const unsigned short* Ab = As + cb * 4096;
    const unsigned short* Bb2 = Bs + cb * 4096;
    bf16x8 af[4], bfv[4];
#pragma unroll
    for (int mi = 0; mi < 4; ++mi) af[mi] = *(const bf16x8*)&Ab[aOff[mi]];
#pragma unroll
    for (int ni = 0; ni < 4; ++ni) bfv[ni] = *(const bf16x8*)&Bb2[bOff[ni]];
#pragma unroll
    for (int mi = 0; mi < 4; ++mi)
#pragma unroll
      for (int ni = 0; ni < 4; ++ni)
        acc[mi][ni] = __builtin_amdgcn_mfma_f32_16x16x32_bf16(af[mi], bfv[ni], acc[mi][ni], 0, 0, 0);
    cb = (cb == 2) ? 0 : cb + 1;
    sb = (sb == 2) ? 0 : sb + 1;
  }

#pragma unroll
  for (int ni = 0; ni < 4; ++ni) {
    const int col = n0 + wn * 64 + ni * 16 + lr;
    const float bv = biasptr[col];
#pragma unroll
    for (int mi = 0; mi < 4; ++mi) {
#pragma unroll
      for (int i = 0; i < 4; ++i) {
        const int mloc = wm * 64 + mi * 16 + lk * 4 + i;
        float v = acc[mi][ni][i] + bv;
        if constexpr (EPI == 0) {
          int t = m0 + mloc;
          int which = col >> 10, jj = col & 1023, hh = jj >> 6, hd = jj & 63;
          int bb = t >> 10, s = t & 1023;
          unsigned short* dst = (which == 0) ? (unsigned short*)o0
                              : (which == 1) ? (unsigned short*)o1 : (unsigned short*)o2;
          dst[((size_t)(bb * Hh + hh) * Sq + s) * HDd + hd] = f2bf(v);
        } else if constexpr (EPI == 1) {
          ((float*)o0)[(size_t)(m0 + mloc) * Dd + col] = v;
        } else {
          ((unsigned short*)o0)[(size_t)(m0 + mloc) * Dd + col] = f2bf(v);
        }
      }
    }
  }
}

// ---------------- flash attention, 64-row q tiles ----------------
__global__ __launch_bounds__(256) void attn_kernel(
    const unsigned short* __restrict__ qb, const unsigned short* __restrict__ kb,
    const unsigned short* __restrict__ vb, const int* __restrict__ mask,
    unsigned short* __restrict__ attnb) {
  const int qt = blockIdx.x, h = blockIdx.y, b = blockIdx.z;
  const unsigned short* Q = qb + (size_t)(b * Hh + h) * Sq * HDd;
  const unsigned short* Kg = kb + (size_t)(b * Hh + h) * Sq * HDd;
  const unsigned short* Vg = vb + (size_t)(b * Hh + h) * Sq * HDd;

  __shared__ unsigned short Qs[64 * 72], Ks[64 * 72], Vt[64 * 72], Ps[64 * 72];
  __shared__ float Ssm[64 * 65];
  __shared__ float mS[64], lS[64], aS[64];
  __shared__ int mk[64];

  const int tid = threadIdx.x, lane = tid & 63, wid = tid >> 6;
  const int lr = lane & 15, lk = lane >> 4;

#pragma unroll
  for (int it = 0; it < 2; ++it) {
    int c = tid + it * 256; int r = c >> 3, kc = (c & 7) * 8;
    *(uint4*)&Qs[r * 72 + kc] = *(const uint4*)(Q + (size_t)(qt * 64 + r) * 64 + kc);
  }
  if (tid < 64) { mS[tid] = -1e30f; lS[tid] = 0.f; }

  f32x4 oacc[4] = {};

  for (int kt = 0; kt < 16; ++kt) {
    __syncthreads();
#pragma unroll
    for (int it = 0; it < 2; ++it) {
      int c = tid + it * 256; int r = c >> 3, kc = (c & 7) * 8;
      *(uint4*)&Ks[r * 72 + kc] = *(const uint4*)(Kg + (size_t)(kt * 64 + r) * 64 + kc);
    }
    {
      int kk = tid >> 2, hg = (tid & 3) * 16;
      union { uint4 u[2]; unsigned short s[16]; } tv;
      tv.u[0] = *(const uint4*)(Vg + (size_t)(kt * 64 + kk) * 64 + hg);
      tv.u[1] = *(const uint4*)(Vg + (size_t)(kt * 64 + kk) * 64 + hg + 8);
#pragma unroll
      for (int j = 0; j < 16; ++j) Vt[(hg + j) * 72 + kk] = tv.s[j];
    }
    if (tid < 64) mk[tid] = mask[b * Sq + kt * 64 + tid];
    __syncthreads();

    f32x4 sacc[4] = {};
#pragma unroll
    for (int ks = 0; ks < 2; ++ks) {
      bf16x8 aq = *(const bf16x8*)&Qs[(wid * 16 + lr) * 72 + ks * 32 + lk * 8];
#pragma unroll
      for (int ni = 0; ni < 4; ++ni) {
        bf16x8 bk = *(const bf16x8*)&Ks[(ni * 16 + lr) * 72 + ks * 32 + lk * 8];
        sacc[ni] = __builtin_amdgcn_mfma_f32_16x16x32_bf16(aq, bk, sacc[ni], 0, 0, 0);
      }
    }
#pragma unroll
    for (int ni = 0; ni < 4; ++ni)
#pragma unroll
      for (int i = 0; i < 4; ++i) {
        int r = wid * 16 + lk * 4 + i, cc = ni * 16 + lr;
        float v = sacc[ni][i] * 0.125f;
        if (mk[cc] == 0) v = -1e30f;
        Ssm[r * 65 + cc] = v;
      }
    __syncthreads();
    {
      int r = tid >> 2, cg = (tid & 3) * 16;
      float xv[16];
#pragma unroll
      for (int j = 0; j < 16; ++j) xv[j] = Ssm[r * 65 + cg + j];
      float mx = xv[0];
#pragma unroll
      for (int j = 1; j < 16; ++j) mx = fmaxf(mx, xv[j]);
      mx = fmaxf(mx, __shfl_xor(mx, 1));
      mx = fmaxf(mx, __shfl_xor(mx, 2));
      float mprev = mS[r];
      float mnew = fmaxf(mprev, mx);
      float sum = 0.f;
      union { uint4 u[2]; unsigned short s[16]; } pb;
#pragma unroll
      for (int j = 0; j < 16; ++j) {
        float pv = expf(xv[j] - mnew);
        sum += pv; pb.s[j] = f2bf(pv);
      }
      sum += __shfl_xor(sum, 1);
      sum += __shfl_xor(sum, 2);
      *(uint4*)&Ps[r * 72 + cg] = pb.u[0];
      *(uint4*)&Ps[r * 72 + cg + 8] = pb.u[1];
      if ((tid & 3) == 0) {
        float alpha = expf(mprev - mnew);
        mS[r] = mnew; aS[r] = alpha; lS[r] = lS[r] * alpha + sum;
      }
    }
    __syncthreads();
#pragma unroll
    for (int ni = 0; ni < 4; ++ni)
#pragma unroll
      for (int i = 0; i < 4; ++i)
        oacc[ni][i] *= aS[wid * 16 + lk * 4 + i];
#pragma unroll
    for (int ks = 0; ks < 2; ++ks) {
      bf16x8 ap = *(const bf16x8*)&Ps[(wid * 16 + lr) * 72 + ks * 32 + lk * 8];
#pragma unroll
      for (int ni = 0; ni < 4; ++ni) {
        bf16x8 bv = *(const bf16x8*)&Vt[(ni * 16 + lr) * 72 + ks * 32 + lk * 8];
        oacc[ni] = __builtin_amdgcn_mfma_f32_16x16x32_bf16(ap, bv, oacc[ni], 0, 0, 0);
      }
    }
  }
  __syncthreads();
#pragma unroll
  for (int ni = 0; ni < 4; ++ni)
#pragma unroll
    for (int i = 0; i < 4; ++i) {
      int r = wid * 16 + lk * 4 + i;
      int q = qt * 64 + r;
      float v = oacc[ni][i] / lS[r];
      attnb[((size_t)(b * Sq + q)) * Dd + h * 64 + ni * 16 + lr] = f2bf(v);
    }
}

// ------- ln1 + gate routing fused: x1 = LN(x + proj); route top-2 -------
__global__ __launch_bounds__(256) void ln1_route_kernel(
    const float* __restrict__ a, const float* __restrict__ b2,
    const float* __restrict__ g, const float* __restrict__ beta,
    const float* __restrict__ gw, const float* __restrict__ gb,
    float* __restrict__ outf, unsigned short* __restrict__ outb,
    int* __restrict__ cnt, int* __restrict__ tokslot, float* __restrict__ wtok) {
  const int t = blockIdx.x, tid = threadIdx.x;
  float4 v = *(const float4*)(a + (size_t)t * Dd + tid * 4);
  {
    float4 u = *(const float4*)(b2 + (size_t)t * Dd + tid * 4);
    v.x += u.x; v.y += u.y; v.z += u.z; v.w += u.w;
  }
  const int lane = tid & 63, wid = tid >> 6;
  float s = v.x + v.y + v.z + v.w;
  for (int sh = 1; sh < 64; sh <<= 1) s += __shfl_xor(s, sh);
  __shared__ float red[4], red2[4];
  __shared__ float gred[4 * Ee];
  if (lane == 0) red[wid] = s;
  __syncthreads();
  float mean = (red[0] + red[1] + red[2] + red[3]) * (1.f / Dd);
  float dx = v.x - mean, dy = v.y - mean, dz = v.z - mean, dw = v.w - mean;
  float q = dx * dx + dy * dy + dz * dz + dw * dw;
  for (int sh = 1; sh < 64; sh <<= 1) q += __shfl_xor(q, sh);
  if (lane == 0) red2[wid] = q;
  __syncthreads();
  float var = (red2[0] + red2[1] + red2[2] + red2[3]) * (1.f / Dd);
  float rstd = rsqrtf(var + 1e-5f);
  float4 gg = *(const float4*)(g + tid * 4);
  float4 bbv = *(const float4*)(beta + tid * 4);
  float4 o;
  o.x = dx * rstd * gg.x + bbv.x;
  o.y = dy * rstd * gg.y + bbv.y;
  o.z = dz * rstd * gg.z + bbv.z;
  o.w = dw * rstd * gg.w + bbv.w;
  *(float4*)(outf + (size_t)t * Dd + tid * 4) = o;
  {
    ushort4 pk; pk.x = f2bf(o.x); pk.y = f2bf(o.y); pk.z = f2bf(o.z); pk.w = f2bf(o.w);
    *(ushort4*)(outb + (size_t)t * Dd + tid * 4) = pk;
  }
  float gacc[Ee];
#pragma unroll
  for (int e = 0; e < Ee; ++e) {
    float4 gv = *(const float4*)(gw + (size_t)e * Dd + tid * 4);
    gacc[e] = o.x * gv.x + o.y * gv.y + o.z * gv.z + o.w * gv.w;
  }
#pragma unroll
  for (int e = 0; e < Ee; ++e)
    for (int sh = 1; sh < 64; sh <<= 1) gacc[e] += __shfl_xor(gacc[e], sh);
  if (lane == 0) {
#pragma unroll
    for (int e = 0; e < Ee; ++e) gred[wid * Ee + e] = gacc[e];
  }
  __syncthreads();
  if (tid == 0) {
    float lg[Ee];
#pragma unroll
    for (int e = 0; e < Ee; ++e)
      lg[e] = gred[e] + gred[Ee + e] + gred[2 * Ee + e] + gred[3 * Ee + e] + gb[e];
    float m = lg[0];
#pragma unroll
    for (int e = 1; e < Ee; ++e) m = fmaxf(m, lg[e]);
    float p[Ee], ssum = 0.f;
#pragma unroll
    for (int e = 0; e < Ee; ++e) { p[e] = expf(lg[e] - m); ssum += p[e]; }
    int e0 = 0;
#pragma unroll
    for (int e = 1; e < Ee; ++e) if (p[e] > p[e0]) e0 = e;
    int e1 = -1;
#pragma unroll
    for (int e = 0; e < Ee; ++e) {
      if (e == e0) continue;
      if (e1 < 0 || p[e] > p[e1]) e1 = e;
    }
    float v0 = p[e0] / ssum, v1 = p[e1] / ssum;
    float wsum = v0 + v1 + 1e-9f;
    wtok[t * 2] = v0 / wsum; wtok[t * 2 + 1] = v1 / wsum;
    int p0 = atomicAdd(&cnt[e0], 1);
    tokslot[e0 * Nn + p0] = t * 2;
    int p1 = atomicAdd(&cnt[e1], 1);
    tokslot[e1 * Nn + p1] = t * 2 + 1;
  }
}

// ---- ln2: x1f + w0*ffp[i0] + w1*ffp[i1] (ffp bf16) -> LN -> out ----
__global__ __launch_bounds__(256) void ln2_kernel(
    const float* __restrict__ x1f, const unsigned short* __restrict__ ffp,
    const int* __restrict__ inv, const float* __restrict__ wtok,
    const float* __restrict__ g, const float* __restrict__ beta,
    float* __restrict__ out) {
  const int t = blockIdx.x, tid = threadIdx.x;
  const int i0 = inv[2 * t], i1 = inv[2 * t + 1];
  const float w0 = wtok[2 * t], w1 = wtok[2 * t + 1];
  float4 v = *(const float4*)(x1f + (size_t)t * Dd + tid * 4);
  ushort4 u0 = *(const ushort4*)(ffp + (size_t)i0 * Dd + tid * 4);
  ushort4 u1 = *(const ushort4*)(ffp + (size_t)i1 * Dd + tid * 4);
  v.x += w0 * bf2f(u0.x) + w1 * bf2f(u1.x);
  v.y += w0 * bf2f(u0.y) + w1 * bf2f(u1.y);
  v.z += w0 * bf2f(u0.z) + w1 * bf2f(u1.z);
  v.w += w0 * bf2f(u0.w) + w1 * bf2f(u1.w);
  const int lane = tid & 63, wid = tid >> 6;
  float s = v.x + v.y + v.z + v.w;
  for (int sh = 1; sh < 64; sh <<= 1) s += __shfl_xor(s, sh);
  __shared__ float red[4], red2[4];
  if (lane == 0) red[wid] = s;
  __syncthreads();
  float mean = (red[0] + red[1] + red[2] + red[3]) * (1.f / Dd);
  float dx = v.x - mean, dy = v.y - mean, dz = v.z - mean, dw = v.w - mean;
  float q = dx * dx + dy * dy + dz * dz + dw * dw;
  for (int sh = 1; sh < 64; sh <<= 1) q += __shfl_xor(q, sh);
  if (lane == 0) red2[wid] = q;
  __syncthreads();
  float var = (red2[0] + red2[1] + red2[2] + red2[3]) * (1.f / Dd);
  float rstd = rsqrtf(var + 1e-5f);
  float4 gg = *(const float4*)(g + tid * 4);
  float4 bb = *(const float4*)(beta + tid * 4);
  float4 o;
  o.x = dx * rstd * gg.x + bb.x;
  o.y = dy * rstd * gg.y + bb.y;
  o.z = dz * rstd * gg.z + bb.z;
  o.w = dw * rstd * gg.w + bb.w;
  *(float4*)(out + (size_t)t * Dd + tid * 4) = o;
}

// poff[e] = 256-aligned cumulative offsets; poff[Ee] = padded total
__global__ void offsets_kernel(const int* __restrict__ cnt, int* __restrict__ poff) {
  if (threadIdx.x == 0) {
    int s = 0;
    for (int e = 0; e < Ee; ++e) { poff[e] = s; s += (cnt[e] + 255) & ~255; }
    poff[Ee] = s;
  }
}

// ---------------- pack: gather x1b rows into padded xg, build inverse map ----------------
__global__ __launch_bounds__(256) void pack_kernel(
    const unsigned short* __restrict__ x1b, const int* __restrict__ tokslot,
    const int* __restrict__ cnt, const int* __restrict__ poff,
    unsigned short* __restrict__ xg, int* __restrict__ inv) {
  const int tid = threadIdx.x;
  const int g = blockIdx.x * 8 + (tid >> 5);
  const int l = tid & 31;
  if (g >= poff[Ee]) return;
  int e = 0;
#pragma unroll
  for (int k = 1; k < Ee; ++k) if (g >= poff[k]) e = k;
  const int pos = g - poff[e];
  uint4* dst = (uint4*)(xg + (size_t)g * Dd);
  if (pos < cnt[e]) {
    const int ent = tokslot[e * Nn + pos];
    if (l == 0) inv[ent] = g;
    const uint4* src = (const uint4*)(x1b + (size_t)(ent >> 1) * Dd);
#pragma unroll
    for (int j = 0; j < 4; ++j) dst[l + j * 32] = src[l + j * 32];
  } else {
    const uint4 z = make_uint4(0, 0, 0, 0);
#pragma unroll
    for (int j = 0; j < 4; ++j) dst[l + j * 32] = z;
  }
}

// ---------------- launch ----------------
extern "C" void kernel_launch(void* const* d_in, const int* in_sizes, int n_in,
                              void* d_out, int out_size, void* d_ws, size_t ws_size,
                              hipStream_t stream) {
  const float* x   = (const float*)d_in[0];
  const int*   msk = (const int*)d_in[1];
  const float* ipw = (const float*)d_in[2];
  const float* ipb = (const float*)d_in[3];
  const float* opw = (const float*)d_in[4];
  const float* opb = (const float*)d_in[5];
  const float* g1  = (const float*)d_in[6];
  const float* be1 = (const float*)d_in[7];
  const float* g2  = (const float*)d_in[8];
  const float* be2 = (const float*)d_in[9];
  const float* gw  = (const float*)d_in[10];
  const float* gb  = (const float*)d_in[11];
  const float* w1  = (const float*)d_in[12];
  const float* b1  = (const float*)d_in[13];
  const float* w2  = (const float*)d_in[14];
  const float* b2  = (const float*)d_in[15];
  float* out = (float*)d_out;

  char* p = (char*)d_ws;
  auto carve = [&](size_t bytes) { char* r = p; p += (bytes + 255) & ~(size_t)255; return r; };
  unsigned short* xb   = (unsigned short*)carve((size_t)Nn * Dd * 2);  // also attnb
  unsigned short* qb   = (unsigned short*)carve((size_t)Nn * Dd * 2);
  unsigned short* kb   = (unsigned short*)carve((size_t)Nn * Dd * 2);
  unsigned short* vb   = (unsigned short*)carve((size_t)Nn * Dd * 2);
  float* proj          = (float*)carve((size_t)Nn * Dd * 4);
  float* x1f           = (float*)carve((size_t)Nn * Dd * 4);
  unsigned short* x1b  = (unsigned short*)carve((size_t)Nn * Dd * 2);
  unsigned short* xg   = (unsigned short*)carve((size_t)PMAX * Dd * 2);
  unsigned short* ffp  = (unsigned short*)carve((size_t)PMAX * Dd * 2);
  unsigned short* hbuf = (unsigned short*)carve((size_t)PMAX * Ff * 2);
  unsigned short* wbuf = (unsigned short*)carve((size_t)Ee * Ff * Dd * 2);
  int* cnt             = (int*)carve(64);
  int* poff            = (int*)carve(64);
  int* tokslot         = (int*)carve((size_t)Ee * Nn * 4);
  float* wtok          = (float*)carve((size_t)2 * Nn * 4);
  int* inv             = (int*)carve((size_t)2 * Nn * 4);
  unsigned short* attnb = xb;

  cvt_kernel<<<Nn * Dd / 2048, 256, 0, stream>>>(x, xb);
  cvt_kernel<<<TD * Dd / 2048, 256, 0, stream>>>(ipw, wbuf);
  gemm_bt<0><<<dim3(Nn / 128, TD / 128), 256, 0, stream>>>(
      xb, wbuf, ipb, qb, kb, vb, Nn, TD, Dd, nullptr);
  attn_kernel<<<dim3(Sq / 64, Hh, Bb), 256, 0, stream>>>(qb, kb, vb, msk, attnb);
  cvt_kernel<<<Dd * Dd / 2048, 256, 0, stream>>>(opw, wbuf);
  gemm_bt<1><<<dim3(Nn / 128, Dd / 128), 256, 0, stream>>>(
      attnb, wbuf, opb, proj, nullptr, nullptr, Nn, Dd, Dd, nullptr);
  hipMemsetAsync(cnt, 0, 64, stream);
  ln1_route_kernel<<<Nn, 256, 0, stream>>>(x, proj, g1, be1, gw, gb,
                                           x1f, x1b, cnt, tokslot, wtok);
  offsets_kernel<<<1, 64, 0, stream>>>(cnt, poff);
  pack_kernel<<<PMAX / 8, 256, 0, stream>>>(x1b, tokslot, cnt, poff, xg, inv);
  cvt_kernel<<<Ee * Ff * Dd / 2048, 256, 0, stream>>>(w1, wbuf);
  gemm8p_up<<<dim3(PMAX / 256, Ff / 256), 512, 0, stream>>>(xg, wbuf, b1, hbuf, poff);
  cvt_kernel<<<Ee * Dd * Ff / 2048, 256, 0, stream>>>(w2, wbuf);
  gemm_bt<3><<<dim3(PMAX / 128, Dd / 128), 256, 0, stream>>>(
      hbuf, wbuf, b2, ffp, nullptr, nullptr, PMAX, Dd, Ff, poff);
  ln2_kernel<<<Nn, 256, 0, stream>>>(x1f, ffp, inv, wtok, g2, be2, out);
}